// Round 11
// baseline (596.837 us; speedup 1.0000x reference)
//
#include <hip/hip_runtime.h>
#include <hip/hip_fp16.h>

#define NCELLS 256
#define GRID_MIN_F (-10.0f)
#define INV_DX 12.75f               // 255/20, binary-exact
#define NBINS2 2048                 // 16 x 16 x 8 coarse bins of 16x16x32 cells
#define NP3 256                     // 1 block/CU (136KB LDS), all resident
#define NT3 1024
#define NT4 512
#define NGRP 8
#define CAP3 760                    // slots per (grp,cbin): ~610 real + ~49 pads + ~4sigma; mult of 4
#define SPILL_CAP 262144
#define RING 8                      // LDS slots per bin; flush unit 4 (32B aligned)

// p4 accumulator: 4 parity copies (py,pz), each 17(x) x 8(wy) x 16(wz) u64 words
#define W_Y2 8
#define W_Z2 16
#define NWORDS2 (4 * 17 * W_Y2 * W_Z2)    // 8704 u64 = 69632 B
#define TX 17
#define TY 17
#define TZ 33
#define TILE3B (TX * TY * TZ)             // 9537 cells per coarse tile

typedef float f32x4 __attribute__((ext_vector_type(4)));

__device__ __forceinline__ bool cell_of(
    float x, float y, float z,
    float& fx, float& fy, float& fz,
    int& cx, int& cy, int& cz)
{
    fx = (x - GRID_MIN_F) * INV_DX;
    fy = (y - GRID_MIN_F) * INV_DX;
    fz = (z - GRID_MIN_F) * INV_DX;
    cx = (int)floorf(fx);
    cy = (int)floorf(fy);
    cz = (int)floorf(fz);
    return (cx >= 0) && (cx < NCELLS) && (cy >= 0) && (cy < NCELLS) &&
           (cz >= 0) && (cz < NCELLS);
}

__device__ __forceinline__ void spill_f4(
    float fx, float fy, float fz, float w,
    unsigned* __restrict__ spillcnt, float4* __restrict__ spill)
{
    unsigned sp = atomicAdd(spillcnt, 1u);
    if (sp < SPILL_CAP) spill[sp] = make_float4(fx, fy, fz, w);
}

// spill a staged record (reconstruct grid-unit coords from quantized form)
__device__ __forceinline__ void spill_rec(
    uint2 r, int b,
    unsigned* __restrict__ spillcnt, float4* __restrict__ spill)
{
    int bx = b >> 7, by = (b >> 3) & 15, bzc = b & 7;
    float fx = (float)(bx << 4) + (float)(r.x & 0xffffu) * (1.0f / 4096.0f);
    float fy = (float)(by << 4) + (float)(r.x >> 16) * (1.0f / 4096.0f);
    float fz = (float)(bzc << 5) + (float)(r.y & 0xffffu) * (1.0f / 2048.0f);
    float w = __half2float(__ushort_as_half((unsigned short)(r.y >> 16)));
    if (w != 0.0f) spill_f4(fx, fy, fz, w, spillcnt, spill);
}

__device__ __forceinline__ void stage_one(
    float x, float y, float z, float w,
    unsigned* __restrict__ cnt, uint2 (*__restrict__ buf)[RING],
    unsigned* __restrict__ spillcnt, float4* __restrict__ spill)
{
    float fx, fy, fz; int cx, cy, cz;
    if (!cell_of(x, y, z, fx, fy, fz, cx, cy, cz)) return;
    int bx = cx >> 4, by = cy >> 4, bzc = cz >> 5;
    int b = (bx * 16 + by) * 8 + bzc;

    float lx = fx - (float)(bx << 4);
    float ly = fy - (float)(by << 4);
    float lz = fz - (float)(bzc << 5);
    unsigned qx = min((unsigned)(lx * 4096.0f), 65535u);
    unsigned qy = min((unsigned)(ly * 4096.0f), 65535u);
    unsigned qz = min((unsigned)(lz * 2048.0f), 65535u);  // 5-bit cell + 11-bit frac
    uint2 r;
    r.x = qx | (qy << 16);
    r.y = qz | ((unsigned)__half_as_ushort(__float2half(w)) << 16);

    unsigned t = atomicAdd(&cnt[b], 1u);
    if (t < (unsigned)RING) buf[b][t] = r;                // slot visible after barrier
    else spill_f4(fx, fy, fz, w, spillcnt, spill);        // ring overflow (~1e-5)
}

// ---------- p3: single-pass, LDS write-combine, 32B-aligned flushes ----------
__global__ __launch_bounds__(NT3) void p3_stage(
    const float* __restrict__ pos, const float* __restrict__ wgt, int n, int chunk,
    unsigned* __restrict__ gcur /* [NGRP][NBINS2] */,
    unsigned* __restrict__ spillcnt,
    uint2* __restrict__ rec /* [NGRP][NBINS2][CAP3] */,
    float4* __restrict__ spill)
{
    __shared__ uint2 buf[NBINS2][RING];    // 128 KB
    __shared__ unsigned cnt[NBINS2];       // 8 KB
    for (int i = threadIdx.x; i < NBINS2; i += NT3) cnt[i] = 0;
    __syncthreads();

    int grp = blockIdx.x & (NGRP - 1);
    unsigned* mycur = gcur + grp * NBINS2;
    uint2* myrec = rec + (size_t)grp * NBINS2 * CAP3;

    int start = blockIdx.x * chunk;        // chunk % 4 == 0
    int end = min(start + chunk, n);
    const f32x4* __restrict__ pos4 = (const f32x4*)pos;
    const f32x4* __restrict__ wgt4 = (const f32x4*)wgt;
    int p0 = start >> 2;
    int p1 = max(end, start) >> 2;
    int nep = (p1 - p0 + NT3 - 1) / NT3;

    for (int e = 0; e < nep; ++e) {
        int p = p0 + e * NT3 + (int)threadIdx.x;
        if (p < p1) {
            f32x4 a = pos4[3 * (size_t)p + 0];
            f32x4 b4 = pos4[3 * (size_t)p + 1];
            f32x4 c = pos4[3 * (size_t)p + 2];
            f32x4 w4 = wgt4[p];
            stage_one(a.x, a.y, a.z, w4.x, cnt, buf, spillcnt, spill);
            stage_one(a.w, b4.x, b4.y, w4.y, cnt, buf, spillcnt, spill);
            stage_one(b4.z, b4.w, c.x, w4.z, cnt, buf, spillcnt, spill);
            stage_one(c.y, c.z, c.w, w4.w, cnt, buf, spillcnt, spill);
        }
        __syncthreads();
        // flush full 32B groups; carry <=3 leftovers
        for (int b = threadIdx.x; b < NBINS2; b += NT3) {
            unsigned c2 = min(cnt[b], (unsigned)RING);
            unsigned full = c2 & ~3u;
            if (full) {
                unsigned base = atomicAdd(&mycur[b], full);
                for (unsigned g = 0; g < full; g += 4) {
                    if (base + g + 4 <= (unsigned)CAP3) {
                        uint4* dst = (uint4*)(myrec + (size_t)b * CAP3 + base + g);
                        dst[0] = *(const uint4*)&buf[b][g];
                        dst[1] = *(const uint4*)&buf[b][g + 2];
                    } else {
                        for (unsigned j = 0; j < 4; ++j) {
                            unsigned s = base + g + j;
                            if (s < (unsigned)CAP3) myrec[(size_t)b * CAP3 + s] = buf[b][g + j];
                            else spill_rec(buf[b][g + j], b, spillcnt, spill);
                        }
                    }
                }
                unsigned left = c2 - full;
                for (unsigned j = 0; j < left; ++j) buf[b][j] = buf[b][full + j];
                cnt[b] = left;
            }
        }
        __syncthreads();
    }

    // drain: pad leftover (<=3) to a full 32B group with zero-weight records
    for (int b = threadIdx.x; b < NBINS2; b += NT3) {
        unsigned c2 = cnt[b];
        if (c2) {
            for (unsigned j = c2; j < 4; ++j) buf[b][j] = make_uint2(0u, 0u);
            unsigned base = atomicAdd(&mycur[b], 4u);
            if (base + 4 <= (unsigned)CAP3) {
                uint4* dst = (uint4*)(myrec + (size_t)b * CAP3 + base);
                dst[0] = *(const uint4*)&buf[b][0];
                dst[1] = *(const uint4*)&buf[b][2];
            } else {
                for (unsigned j = 0; j < 4; ++j) {
                    unsigned s = base + j;
                    if (s < (unsigned)CAP3) myrec[(size_t)b * CAP3 + s] = buf[b][j];
                    else if (j < c2) spill_rec(buf[b][j], b, spillcnt, spill);
                }
            }
        }
    }

    // global tail (n % 4 != 0): direct spill, <=3 particles total
    for (int i = (p1 << 2) + (int)threadIdx.x; i < end; i += NT3) {
        float fx, fy, fz; int cx, cy, cz;
        if (cell_of(pos[3 * (size_t)i + 0], pos[3 * (size_t)i + 1],
                    pos[3 * (size_t)i + 2], fx, fy, fz, cx, cy, cz))
            spill_f4(fx, fy, fz, wgt[i], spillcnt, spill);
    }
}

// ---------- p4: deposit per coarse bin (16x16x32), u64-packed LDS atomics ----------
__global__ __launch_bounds__(NT4) void p4_deposit(
    const uint2* __restrict__ rec, const unsigned* __restrict__ gcur,
    __half* __restrict__ tiles /* [NBINS2][TILE3B] */)
{
    __shared__ unsigned long long acc[NWORDS2];
    int bid = blockIdx.x;
    for (int i = threadIdx.x; i < NWORDS2; i += NT4) acc[i] = 0ull;
    __syncthreads();

    const float inv12 = 1.0f / 4096.0f;
    const float inv11 = 1.0f / 2048.0f;
    for (int g = 0; g < NGRP; ++g) {
        unsigned e = min(gcur[g * NBINS2 + bid], (unsigned)CAP3);
        const uint2* rb = rec + ((size_t)g * NBINS2 + bid) * CAP3;
        for (unsigned idx = threadIdx.x; idx < e; idx += NT4) {
            uint2 r = rb[idx];
            unsigned qx = r.x & 0xffffu, qy = r.x >> 16;
            unsigned qz = r.y & 0xffffu;
            float w = __half2float(__ushort_as_half((unsigned short)(r.y >> 16)));
            int lx = qx >> 12, ly = qy >> 12, lz = qz >> 11;
            float ox = (float)(qx & 4095u) * inv12;
            float oy = (float)(qy & 4095u) * inv12;
            float oz = (float)(qz & 2047u) * inv11;

            float wx0 = w * (1.0f - ox), wx1 = w * ox;
            float wy0 = 1.0f - oy, wy1 = oy;
            float wz0 = 1.0f - oz, wz1 = oz;
            float q00 = wy0 * wz0, q01 = wy0 * wz1, q10 = wy1 * wz0, q11 = wy1 * wz1;

            int py = ly & 1, pz = lz & 1;
            int wy = ly >> 1, wz = lz >> 1;
            int copy = py * 2 + pz;
            int wbase = ((copy * 17 + lx) * W_Y2 + wy) * W_Z2 + wz;

            unsigned long long v0 =
                (unsigned long long)(unsigned)(wx0 * q00 * 8192.0f + 0.5f)
              | ((unsigned long long)(unsigned)(wx0 * q01 * 8192.0f + 0.5f) << 16)
              | ((unsigned long long)(unsigned)(wx0 * q10 * 8192.0f + 0.5f) << 32)
              | ((unsigned long long)(unsigned)(wx0 * q11 * 8192.0f + 0.5f) << 48);
            unsigned long long v1 =
                (unsigned long long)(unsigned)(wx1 * q00 * 8192.0f + 0.5f)
              | ((unsigned long long)(unsigned)(wx1 * q01 * 8192.0f + 0.5f) << 16)
              | ((unsigned long long)(unsigned)(wx1 * q10 * 8192.0f + 0.5f) << 32)
              | ((unsigned long long)(unsigned)(wx1 * q11 * 8192.0f + 0.5f) << 48);

            atomicAdd(&acc[wbase], v0);
            atomicAdd(&acc[wbase + W_Y2 * W_Z2], v1);   // lx+1
        }
    }
    __syncthreads();

    __half* out = tiles + (size_t)bid * TILE3B;
    for (int f = threadIdx.x; f < TILE3B; f += NT4) {
        int tz = f % TZ;
        int r2 = f / TZ;
        int ty = r2 % TY;
        int tx = r2 / TY;
        unsigned sum = 0;
        #pragma unroll
        for (int dy = 0; dy < 2; ++dy) {
            int ly = ty - dy;
            if (ly < 0 || ly > 15) continue;
            int py = ly & 1, wy = ly >> 1;
            #pragma unroll
            for (int dz = 0; dz < 2; ++dz) {
                int lz = tz - dz;
                if (lz < 0 || lz > 31) continue;
                int pz = lz & 1, wz = lz >> 1;
                int copy = py * 2 + pz;
                unsigned long long wv =
                    acc[((copy * 17 + tx) * W_Y2 + wy) * W_Z2 + wz];
                sum += (unsigned)((wv >> (16 * (2 * dy + dz))) & 0xffffull);
            }
        }
        out[f] = __float2half((float)sum * (1.0f / 8192.0f));
    }
}

// ---------- p5: gather tiles -> grid ----------
__global__ __launch_bounds__(256) void p5_gather(
    const __half* __restrict__ tiles, float* __restrict__ grid)
{
    int f = blockIdx.x * blockDim.x + threadIdx.x;
    int gz = f & 255;
    int gy = (f >> 8) & 255;
    int gx = f >> 16;

    int bx = gx >> 4, tx = gx & 15;
    int by = gy >> 4, ty = gy & 15;
    int bz = gz >> 5, tz = gz & 31;

    int nx = (tx == 0 && bx > 0) ? 2 : 1;
    int ny = (ty == 0 && by > 0) ? 2 : 1;
    int nz = (tz == 0 && bz > 0) ? 2 : 1;

    float v = 0.0f;
    for (int ax = 0; ax < nx; ++ax) {
        int bbx = bx - ax, ttx = ax ? 16 : tx;
        for (int ay = 0; ay < ny; ++ay) {
            int bby = by - ay, tty = ay ? 16 : ty;
            for (int az = 0; az < nz; ++az) {
                int bbz = bz - az, ttz = az ? 32 : tz;
                size_t bin = (size_t)(bbx * 16 + bby) * 8 + bbz;
                v += __half2float(tiles[bin * TILE3B + (ttx * TY + tty) * TZ + ttz]);
            }
        }
    }
    grid[f] = v;
}

// ---------- p6: spill tail (grid-unit float4 records) ----------
__global__ __launch_bounds__(256) void p6_spill(
    const unsigned* __restrict__ spillcnt, const float4* __restrict__ spill,
    float* __restrict__ grid)
{
    unsigned c = min(*spillcnt, (unsigned)SPILL_CAP);
    for (unsigned i = blockIdx.x * blockDim.x + threadIdx.x; i < c;
         i += gridDim.x * blockDim.x) {
        float4 r = spill[i];
        float fx = r.x, fy = r.y, fz = r.z, w = r.w;
        int cx = (int)floorf(fx), cy = (int)floorf(fy), cz = (int)floorf(fz);
        float ox = fx - floorf(fx), oy = fy - floorf(fy), oz = fz - floorf(fz);
        float wx0 = w * (1.0f - ox), wx1 = w * ox;
        float wy0 = 1.0f - oy, wy1 = oy;
        float wz0 = 1.0f - oz, wz1 = oz;
        bool bx1 = cx + 1 < NCELLS, by1 = cy + 1 < NCELLS, bz1 = cz + 1 < NCELLS;
        long base = ((long)cx * NCELLS + cy) * NCELLS + cz;
        atomicAdd(&grid[base], wx0 * wy0 * wz0);
        if (bz1) atomicAdd(&grid[base + 1], wx0 * wy0 * wz1);
        if (by1) {
            atomicAdd(&grid[base + NCELLS], wx0 * wy1 * wz0);
            if (bz1) atomicAdd(&grid[base + NCELLS + 1], wx0 * wy1 * wz1);
        }
        if (bx1) {
            long basex = base + (long)NCELLS * NCELLS;
            atomicAdd(&grid[basex], wx1 * wy0 * wz0);
            if (bz1) atomicAdd(&grid[basex + 1], wx1 * wy0 * wz1);
            if (by1) {
                atomicAdd(&grid[basex + NCELLS], wx1 * wy1 * wz0);
                if (bz1) atomicAdd(&grid[basex + NCELLS + 1], wx1 * wy1 * wz1);
            }
        }
    }
}

// ---------- Fallback ----------
__global__ __launch_bounds__(256) void cic_naive(
    const float* __restrict__ pos, const float* __restrict__ wgt,
    float* __restrict__ grid, int n)
{
    int i = blockIdx.x * blockDim.x + threadIdx.x;
    if (i >= n) return;
    float fx, fy, fz; int cx, cy, cz;
    if (!cell_of(pos[3 * (size_t)i + 0], pos[3 * (size_t)i + 1],
                 pos[3 * (size_t)i + 2], fx, fy, fz, cx, cy, cz)) return;
    float w = wgt[i];
    float ox = fx - floorf(fx), oy = fy - floorf(fy), oz = fz - floorf(fz);
    float wx0 = w * (1.0f - ox), wx1 = w * ox;
    float wy0 = 1.0f - oy, wy1 = oy;
    float wz0 = 1.0f - oz, wz1 = oz;
    bool bx1 = cx + 1 < NCELLS, by1 = cy + 1 < NCELLS, bz1 = cz + 1 < NCELLS;
    long base = ((long)cx * NCELLS + cy) * NCELLS + cz;
    atomicAdd(&grid[base], wx0 * wy0 * wz0);
    if (bz1) atomicAdd(&grid[base + 1], wx0 * wy0 * wz1);
    if (by1) {
        atomicAdd(&grid[base + NCELLS], wx0 * wy1 * wz0);
        if (bz1) atomicAdd(&grid[base + NCELLS + 1], wx0 * wy1 * wz1);
    }
    if (bx1) {
        long basex = base + (long)NCELLS * NCELLS;
        atomicAdd(&grid[basex], wx1 * wy0 * wz0);
        if (bz1) atomicAdd(&grid[basex + 1], wx1 * wy0 * wz1);
        if (by1) {
            atomicAdd(&grid[basex + NCELLS], wx1 * wy1 * wz0);
            if (bz1) atomicAdd(&grid[basex + NCELLS + 1], wx1 * wy1 * wz1);
        }
    }
}

extern "C" void kernel_launch(void* const* d_in, const int* in_sizes, int n_in,
                              void* d_out, int out_size, void* d_ws, size_t ws_size,
                              hipStream_t stream) {
    const float* positions = (const float*)d_in[0];
    const float* weights   = (const float*)d_in[1];
    float* grid            = (float*)d_out;
    int n = in_sizes[1];

    // ws: [gcur 8*2048*4=64KB][spillcnt][pad to 1MB][tiles f16 39.06MB]
    //     [rec 8*2048*760*8=99.61MB][spill 4MB]  ~143.9MB
    const size_t gcur_off   = 0;
    const size_t spillc_off = (size_t)NGRP * NBINS2 * sizeof(unsigned);
    const size_t tiles_off  = 1024 * 1024;
    const size_t tiles_bytes = (size_t)NBINS2 * TILE3B * sizeof(__half);
    const size_t rec_off    = tiles_off + tiles_bytes;
    const size_t rec_bytes  = (size_t)NGRP * NBINS2 * CAP3 * sizeof(uint2);
    const size_t spill_off  = rec_off + rec_bytes;
    const size_t ws_needed  = spill_off + (size_t)SPILL_CAP * sizeof(float4);

    if (ws_size < ws_needed) {
        hipMemsetAsync(grid, 0, (size_t)out_size * sizeof(float), stream);
        cic_naive<<<(n + 255) / 256, 256, 0, stream>>>(positions, weights, grid, n);
        return;
    }

    unsigned* gcur     = (unsigned*)((char*)d_ws + gcur_off);
    unsigned* spillcnt = (unsigned*)((char*)d_ws + spillc_off);
    __half*   tiles    = (__half*)((char*)d_ws + tiles_off);
    uint2*    rec      = (uint2*)((char*)d_ws + rec_off);
    float4*   spill    = (float4*)((char*)d_ws + spill_off);

    hipMemsetAsync(gcur, 0, ((size_t)NGRP * NBINS2 + 1) * sizeof(unsigned), stream);

    int chunk = (((n + NP3 - 1) / NP3) + 3) & ~3;   // multiple of 4 for float4 packs
    p3_stage <<<NP3, NT3, 0, stream>>>(positions, weights, n, chunk,
                                       gcur, spillcnt, rec, spill);
    p4_deposit<<<NBINS2, NT4, 0, stream>>>(rec, gcur, tiles);
    p5_gather <<<(NCELLS * NCELLS * NCELLS) / 256, 256, 0, stream>>>(tiles, grid);
    p6_spill  <<<64, 256, 0, stream>>>(spillcnt, spill, grid);
}

// Round 12
// 439.666 us; speedup vs baseline: 1.3575x; 1.3575x over previous
//
#include <hip/hip_runtime.h>
#include <hip/hip_fp16.h>

#define NCELLS 256
#define GRID_MIN_F (-10.0f)
#define INV_DX 12.75f               // 255/20, binary-exact
#define NBPD 16                     // bins per dim
#define NBINS 4096                  // 16^3, bin = 16^3 cells
#define TILE 17
#define TILE3 (TILE * TILE * TILE)
#define NP3 1024                    // scatter blocks (4/CU -> 32 waves/CU)
#define NT3 512
#define NT4 512
#define NGRP 8                      // XCD groups (blockIdx & 7)
#define CAP2 400                    // slots per (group,bin); mean 305, ~5.4 sigma
#define SPILL_CAP 262144

// staggered packed accumulator: 4 parity copies (py,pz), each 17 x 8 x 8 u64 words
#define W_Y 8
#define W_Z 8
#define NWORDS (4 * 17 * W_Y * W_Z)       // 4352 u64 = 34816 B

__device__ __forceinline__ bool cell_of(
    float x, float y, float z,
    float& fx, float& fy, float& fz,
    int& cx, int& cy, int& cz)
{
    fx = (x - GRID_MIN_F) * INV_DX;
    fy = (y - GRID_MIN_F) * INV_DX;
    fz = (z - GRID_MIN_F) * INV_DX;
    cx = (int)floorf(fx);
    cy = (int)floorf(fy);
    cz = (int)floorf(fz);
    return (cx >= 0) && (cx < NCELLS) && (cy >= 0) && (cy < NCELLS) &&
           (cz >= 0) && (cz < NCELLS);
}

__device__ __forceinline__ void count_one(
    float x, float y, float z, unsigned* __restrict__ hist)
{
    float fx, fy, fz; int cx, cy, cz;
    if (cell_of(x, y, z, fx, fy, fz, cx, cy, cz)) {
        int bid = ((cx >> 4) * NBPD + (cy >> 4)) * NBPD + (cz >> 4);
        atomicAdd(&hist[bid], 1u);
    }
}

__device__ __forceinline__ void scatter_one(
    float x, float y, float z, float w,
    unsigned* __restrict__ hist, uint2* __restrict__ myrec,
    unsigned* __restrict__ spillcnt, float4* __restrict__ spill)
{
    float fx, fy, fz; int cx, cy, cz;
    if (!cell_of(x, y, z, fx, fy, fz, cx, cy, cz)) return;
    int bx = cx >> 4, by = cy >> 4, bz = cz >> 4;
    int bid = (bx * NBPD + by) * NBPD + bz;

    float lx = fx - (float)(bx << 4);
    float ly = fy - (float)(by << 4);
    float lz = fz - (float)(bz << 4);
    unsigned qx = min((unsigned)(lx * 4096.0f), 65535u);
    unsigned qy = min((unsigned)(ly * 4096.0f), 65535u);
    unsigned qz = min((unsigned)(lz * 4096.0f), 65535u);
    __half hw = __float2half(w);
    uint2 r;
    r.x = qx | (qy << 16);
    r.y = qz | ((unsigned)__half_as_ushort(hw) << 16);

    unsigned loc = atomicAdd(&hist[bid], 1u);   // LDS slot; hist holds global base after phase 2
    if (loc < CAP2) {
        myrec[(size_t)bid * CAP2 + loc] = r;
    } else {
        unsigned sp = atomicAdd(spillcnt, 1u);
        if (sp < SPILL_CAP) spill[sp] = make_float4(fx, fy, fz, w);
    }
}

// ---------- Fused count + reserve + scatter (two-phase, 2-pack unrolled) ----------
__global__ __launch_bounds__(NT3) void p3_fused(
    const float* __restrict__ pos, const float* __restrict__ wgt, int n, int chunk,
    unsigned* __restrict__ gcur /* [NGRP][NBINS] */,
    unsigned* __restrict__ spillcnt,
    uint2* __restrict__ rec /* [NGRP][NBINS][CAP2] */,
    float4* __restrict__ spill)
{
    __shared__ unsigned hist[NBINS];
    for (int i = threadIdx.x; i < NBINS; i += NT3) hist[i] = 0;
    __syncthreads();

    int grp = blockIdx.x & (NGRP - 1);
    unsigned* mycur = gcur + (size_t)grp * NBINS;
    uint2* myrec = rec + (size_t)grp * NBINS * CAP2;

    int start = blockIdx.x * chunk;             // chunk % 4 == 0
    int end = min(start + chunk, n);

    const float4* __restrict__ pos4 = (const float4*)pos;
    const float4* __restrict__ wgt4 = (const float4*)wgt;
    int p0 = start >> 2;
    int p1 = max(end, start) >> 2;              // full packs; tail only in last block

    // phase 1: count (2 packs in flight per iteration)
    for (int p = p0 + (int)threadIdx.x; p < p1; p += 2 * NT3) {
        int q = p + NT3;
        bool h2 = q < p1;
        float4 a0 = pos4[3 * (size_t)p + 0];
        float4 b0 = pos4[3 * (size_t)p + 1];
        float4 c0 = pos4[3 * (size_t)p + 2];
        float4 a1, b1, c1;
        if (h2) {
            a1 = pos4[3 * (size_t)q + 0];
            b1 = pos4[3 * (size_t)q + 1];
            c1 = pos4[3 * (size_t)q + 2];
        }
        count_one(a0.x, a0.y, a0.z, hist);
        count_one(a0.w, b0.x, b0.y, hist);
        count_one(b0.z, b0.w, c0.x, hist);
        count_one(c0.y, c0.z, c0.w, hist);
        if (h2) {
            count_one(a1.x, a1.y, a1.z, hist);
            count_one(a1.w, b1.x, b1.y, hist);
            count_one(b1.z, b1.w, c1.x, hist);
            count_one(c1.y, c1.z, c1.w, hist);
        }
    }
    for (int i = (p1 << 2) + (int)threadIdx.x; i < end; i += NT3) {
        count_one(pos[3 * (size_t)i + 0], pos[3 * (size_t)i + 1],
                  pos[3 * (size_t)i + 2], hist);
    }
    __syncthreads();

    // phase 2: reserve contiguous per-(group,bin) ranges
    for (int b = threadIdx.x; b < NBINS; b += NT3) {
        unsigned h = hist[b];
        hist[b] = h ? atomicAdd(&mycur[b], h) : 0u;
    }
    __syncthreads();

    // phase 3: scatter records (2 packs in flight per iteration)
    for (int p = p0 + (int)threadIdx.x; p < p1; p += 2 * NT3) {
        int q = p + NT3;
        bool h2 = q < p1;
        float4 a0 = pos4[3 * (size_t)p + 0];
        float4 b0 = pos4[3 * (size_t)p + 1];
        float4 c0 = pos4[3 * (size_t)p + 2];
        float4 w0 = wgt4[p];
        float4 a1, b1, c1, w1;
        if (h2) {
            a1 = pos4[3 * (size_t)q + 0];
            b1 = pos4[3 * (size_t)q + 1];
            c1 = pos4[3 * (size_t)q + 2];
            w1 = wgt4[q];
        }
        scatter_one(a0.x, a0.y, a0.z, w0.x, hist, myrec, spillcnt, spill);
        scatter_one(a0.w, b0.x, b0.y, w0.y, hist, myrec, spillcnt, spill);
        scatter_one(b0.z, b0.w, c0.x, w0.z, hist, myrec, spillcnt, spill);
        scatter_one(c0.y, c0.z, c0.w, w0.w, hist, myrec, spillcnt, spill);
        if (h2) {
            scatter_one(a1.x, a1.y, a1.z, w1.x, hist, myrec, spillcnt, spill);
            scatter_one(a1.w, b1.x, b1.y, w1.y, hist, myrec, spillcnt, spill);
            scatter_one(b1.z, b1.w, c1.x, w1.z, hist, myrec, spillcnt, spill);
            scatter_one(c1.y, c1.z, c1.w, w1.w, hist, myrec, spillcnt, spill);
        }
    }
    for (int i = (p1 << 2) + (int)threadIdx.x; i < end; i += NT3) {
        scatter_one(pos[3 * (size_t)i + 0], pos[3 * (size_t)i + 1],
                    pos[3 * (size_t)i + 2], wgt[i],
                    hist, myrec, spillcnt, spill);
    }
}

// ---------- Deposit: 2 packed u64 LDS atomics per particle; f16 tile flush ----------
__global__ __launch_bounds__(NT4) void p4_deposit(
    const uint2* __restrict__ rec, const unsigned* __restrict__ gcur,
    __half* __restrict__ tiles /* [NBINS][TILE3] */)
{
    __shared__ unsigned long long acc[NWORDS];
    int bid = blockIdx.x;
    for (int i = threadIdx.x; i < NWORDS; i += NT4) acc[i] = 0ull;
    __syncthreads();

    const float inv = 1.0f / 4096.0f;
    for (int g = 0; g < NGRP; ++g) {
        unsigned e = min(gcur[(size_t)g * NBINS + bid], (unsigned)CAP2);
        const uint2* rb = rec + ((size_t)g * NBINS + bid) * CAP2;
        for (unsigned idx = threadIdx.x; idx < e; idx += NT4) {
            uint2 r = rb[idx];
            unsigned qx = r.x & 0xffffu, qy = r.x >> 16;
            unsigned qz = r.y & 0xffffu;
            float w = __half2float(__ushort_as_half((unsigned short)(r.y >> 16)));
            int lx = qx >> 12, ly = qy >> 12, lz = qz >> 12;
            float ox = (float)(qx & 4095u) * inv;
            float oy = (float)(qy & 4095u) * inv;
            float oz = (float)(qz & 4095u) * inv;

            float wx0 = w * (1.0f - ox), wx1 = w * ox;
            float wy0 = 1.0f - oy, wy1 = oy;
            float wz0 = 1.0f - oz, wz1 = oz;
            float q00 = wy0 * wz0, q01 = wy0 * wz1, q10 = wy1 * wz0, q11 = wy1 * wz1;

            int py = ly & 1, pz = lz & 1;
            int wy = (ly - py) >> 1, wz = (lz - pz) >> 1;
            int copy = py * 2 + pz;
            int wbase = ((copy * 17 + lx) * W_Y + wy) * W_Z + wz;

            unsigned long long v0 =
                (unsigned long long)(unsigned)(wx0 * q00 * 8192.0f + 0.5f)
              | ((unsigned long long)(unsigned)(wx0 * q01 * 8192.0f + 0.5f) << 16)
              | ((unsigned long long)(unsigned)(wx0 * q10 * 8192.0f + 0.5f) << 32)
              | ((unsigned long long)(unsigned)(wx0 * q11 * 8192.0f + 0.5f) << 48);
            unsigned long long v1 =
                (unsigned long long)(unsigned)(wx1 * q00 * 8192.0f + 0.5f)
              | ((unsigned long long)(unsigned)(wx1 * q01 * 8192.0f + 0.5f) << 16)
              | ((unsigned long long)(unsigned)(wx1 * q10 * 8192.0f + 0.5f) << 32)
              | ((unsigned long long)(unsigned)(wx1 * q11 * 8192.0f + 0.5f) << 48);

            atomicAdd(&acc[wbase], v0);
            atomicAdd(&acc[wbase + W_Y * W_Z], v1);   // lx+1
        }
    }
    __syncthreads();

    __half* out = tiles + (size_t)bid * TILE3;
    for (int f = threadIdx.x; f < TILE3; f += NT4) {
        int tz = f % TILE;
        int r2 = f / TILE;
        int ty = r2 % TILE;
        int tx = r2 / TILE;
        unsigned sum = 0;
        #pragma unroll
        for (int dy = 0; dy < 2; ++dy) {
            int ly = ty - dy;
            if (ly < 0 || ly > 15) continue;
            int py = ly & 1, wy = (ly - py) >> 1;
            #pragma unroll
            for (int dz = 0; dz < 2; ++dz) {
                int lz = tz - dz;
                if (lz < 0 || lz > 15) continue;
                int pz = lz & 1, wz = (lz - pz) >> 1;
                int copy = py * 2 + pz;
                unsigned long long wv =
                    acc[((copy * 17 + tx) * W_Y + wy) * W_Z + wz];
                sum += (unsigned)((wv >> (16 * (2 * dy + dz))) & 0xffffull);
            }
        }
        out[f] = __float2half((float)sum * (1.0f / 8192.0f));
    }
}

// ---------- Gather tiles -> grid: 4 cells/thread, float4 store ----------
__global__ __launch_bounds__(256) void p5_gather(
    const __half* __restrict__ tiles, float* __restrict__ grid)
{
    int f = blockIdx.x * blockDim.x + threadIdx.x;   // group of 4 cells along z
    int gz0 = (f & 63) << 2;
    int gy = (f >> 6) & 255;
    int gx = f >> 14;

    int bx = gx >> 4, tx = gx & 15;
    int by = gy >> 4, ty = gy & 15;
    int nx = (tx == 0 && bx > 0) ? 2 : 1;
    int ny = (ty == 0 && by > 0) ? 2 : 1;

    float v[4];
    #pragma unroll
    for (int k = 0; k < 4; ++k) {
        int gz = gz0 + k;
        int bz = gz >> 4, tz = gz & 15;
        int nz = (tz == 0 && bz > 0) ? 2 : 1;
        float s = 0.0f;
        for (int ax = 0; ax < nx; ++ax) {
            int bbx = bx - ax, ttx = ax ? 16 : tx;
            for (int ay = 0; ay < ny; ++ay) {
                int bby = by - ay, tty = ay ? 16 : ty;
                for (int az = 0; az < nz; ++az) {
                    int bbz = bz - az, ttz = az ? 16 : tz;
                    size_t bin = ((size_t)bbx * NBPD + bby) * NBPD + bbz;
                    s += __half2float(tiles[bin * TILE3 + (ttx * TILE + tty) * TILE + ttz]);
                }
            }
        }
        v[k] = s;
    }
    *(float4*)&grid[(size_t)f << 2] = make_float4(v[0], v[1], v[2], v[3]);
}

// ---------- Spill tail ----------
__global__ __launch_bounds__(256) void p6_spill(
    const unsigned* __restrict__ spillcnt, const float4* __restrict__ spill,
    float* __restrict__ grid)
{
    unsigned c = min(*spillcnt, (unsigned)SPILL_CAP);
    for (unsigned i = blockIdx.x * blockDim.x + threadIdx.x; i < c;
         i += gridDim.x * blockDim.x) {
        float4 r = spill[i];
        float fx = r.x, fy = r.y, fz = r.z, w = r.w;
        int cx = (int)floorf(fx), cy = (int)floorf(fy), cz = (int)floorf(fz);
        float ox = fx - floorf(fx), oy = fy - floorf(fy), oz = fz - floorf(fz);
        float wx0 = w * (1.0f - ox), wx1 = w * ox;
        float wy0 = 1.0f - oy, wy1 = oy;
        float wz0 = 1.0f - oz, wz1 = oz;
        bool bx1 = cx + 1 < NCELLS, by1 = cy + 1 < NCELLS, bz1 = cz + 1 < NCELLS;
        long base = ((long)cx * NCELLS + cy) * NCELLS + cz;
        atomicAdd(&grid[base], wx0 * wy0 * wz0);
        if (bz1) atomicAdd(&grid[base + 1], wx0 * wy0 * wz1);
        if (by1) {
            atomicAdd(&grid[base + NCELLS], wx0 * wy1 * wz0);
            if (bz1) atomicAdd(&grid[base + NCELLS + 1], wx0 * wy1 * wz1);
        }
        if (bx1) {
            long basex = base + (long)NCELLS * NCELLS;
            atomicAdd(&grid[basex], wx1 * wy0 * wz0);
            if (bz1) atomicAdd(&grid[basex + 1], wx1 * wy0 * wz1);
            if (by1) {
                atomicAdd(&grid[basex + NCELLS], wx1 * wy1 * wz0);
                if (bz1) atomicAdd(&grid[basex + NCELLS + 1], wx1 * wy1 * wz1);
            }
        }
    }
}

// ---------- Fallback ----------
__global__ __launch_bounds__(256) void cic_naive(
    const float* __restrict__ pos, const float* __restrict__ wgt,
    float* __restrict__ grid, int n)
{
    int i = blockIdx.x * blockDim.x + threadIdx.x;
    if (i >= n) return;
    float fx, fy, fz; int cx, cy, cz;
    if (!cell_of(pos[3 * (size_t)i + 0], pos[3 * (size_t)i + 1],
                 pos[3 * (size_t)i + 2], fx, fy, fz, cx, cy, cz)) return;
    float w = wgt[i];
    float ox = fx - floorf(fx), oy = fy - floorf(fy), oz = fz - floorf(fz);
    float wx0 = w * (1.0f - ox), wx1 = w * ox;
    float wy0 = 1.0f - oy, wy1 = oy;
    float wz0 = 1.0f - oz, wz1 = oz;
    bool bx1 = cx + 1 < NCELLS, by1 = cy + 1 < NCELLS, bz1 = cz + 1 < NCELLS;
    long base = ((long)cx * NCELLS + cy) * NCELLS + cz;
    atomicAdd(&grid[base], wx0 * wy0 * wz0);
    if (bz1) atomicAdd(&grid[base + 1], wx0 * wy0 * wz1);
    if (by1) {
        atomicAdd(&grid[base + NCELLS], wx0 * wy1 * wz0);
        if (bz1) atomicAdd(&grid[base + NCELLS + 1], wx0 * wy1 * wz1);
    }
    if (bx1) {
        long basex = base + (long)NCELLS * NCELLS;
        atomicAdd(&grid[basex], wx1 * wy0 * wz0);
        if (bz1) atomicAdd(&grid[basex + 1], wx1 * wy0 * wz1);
        if (by1) {
            atomicAdd(&grid[basex + NCELLS], wx1 * wy1 * wz0);
            if (bz1) atomicAdd(&grid[basex + NCELLS + 1], wx1 * wy1 * wz1);
        }
    }
}

extern "C" void kernel_launch(void* const* d_in, const int* in_sizes, int n_in,
                              void* d_out, int out_size, void* d_ws, size_t ws_size,
                              hipStream_t stream) {
    const float* positions = (const float*)d_in[0];
    const float* weights   = (const float*)d_in[1];
    float* grid            = (float*)d_out;
    int n = in_sizes[1];

    // ws: [gcur 8*4096*4=128KB][spillcnt][pad to 1MB][tiles f16 40.25MB]
    //     [rec 8*4096*400*8=104.86MB][spill 4MB]  ~150MB
    const size_t gcur_off   = 0;
    const size_t spillc_off = (size_t)NGRP * NBINS * sizeof(unsigned);
    const size_t tiles_off  = 1024 * 1024;
    const size_t tiles_bytes = (size_t)NBINS * TILE3 * sizeof(__half);
    const size_t rec_off    = tiles_off + tiles_bytes;
    const size_t rec_bytes  = (size_t)NGRP * NBINS * CAP2 * sizeof(uint2);
    const size_t spill_off  = rec_off + rec_bytes;
    const size_t ws_needed  = spill_off + (size_t)SPILL_CAP * sizeof(float4);

    if (ws_size < ws_needed) {
        hipMemsetAsync(grid, 0, (size_t)out_size * sizeof(float), stream);
        cic_naive<<<(n + 255) / 256, 256, 0, stream>>>(positions, weights, grid, n);
        return;
    }

    unsigned* gcur     = (unsigned*)((char*)d_ws + gcur_off);
    unsigned* spillcnt = (unsigned*)((char*)d_ws + spillc_off);
    __half*   tiles    = (__half*)((char*)d_ws + tiles_off);
    uint2*    rec      = (uint2*)((char*)d_ws + rec_off);
    float4*   spill    = (float4*)((char*)d_ws + spill_off);

    hipMemsetAsync(gcur, 0, ((size_t)NGRP * NBINS + 1) * sizeof(unsigned), stream);

    int chunk = (((n + NP3 - 1) / NP3) + 3) & ~3;   // multiple of 4 for float4 packs
    p3_fused <<<NP3, NT3, 0, stream>>>(positions, weights, n, chunk,
                                       gcur, spillcnt, rec, spill);
    p4_deposit<<<NBINS, NT4, 0, stream>>>(rec, gcur, tiles);
    p5_gather <<<(NCELLS * NCELLS * NCELLS / 4) / 256, 256, 0, stream>>>(tiles, grid);
    p6_spill  <<<64, 256, 0, stream>>>(spillcnt, spill, grid);
}